// Round 1
// baseline (696.355 us; speedup 1.0000x reference)
//
#include <hip/hip_runtime.h>
#include <hip/hip_bf16.h>
#include <math.h>

#define N_NODE 50000
#define N_MOL  1024
#define C_DIM  128
#define P_DIM  64
#define M_DIM  128

// ---------------------------------------------------------------------------
// K0: derive per-node molecule assignment from the one-hot matrix.
// Early-exit scan: column i of mat has exactly one 1.0 at row assign[i].
// Consecutive threads read consecutive addresses per row -> coalesced.
__global__ __launch_bounds__(256) void k_assign(const float* __restrict__ mat,
                                                int* __restrict__ assign,
                                                int* __restrict__ counts) {
    int i = blockIdx.x * blockDim.x + threadIdx.x;
    if (i >= N_NODE) return;
    int mf = 0;
    for (int m = 0; m < N_MOL; ++m) {
        if (mat[(size_t)m * N_NODE + i] > 0.5f) { mf = m; break; }
    }
    assign[i] = mf;
    atomicAdd(&counts[mf], 1);
}

// K1: exclusive prefix sum of counts -> offsets (single block, 1024 threads)
__global__ __launch_bounds__(1024) void k_scan(const int* __restrict__ counts,
                                               int* __restrict__ offsets) {
    __shared__ int s[N_MOL];
    int t = threadIdx.x;
    s[t] = counts[t];
    __syncthreads();
    for (int d = 1; d < N_MOL; d <<= 1) {
        int v = (t >= d) ? s[t - d] : 0;
        __syncthreads();
        s[t] += v;
        __syncthreads();
    }
    offsets[t + 1] = s[t];
    if (t == 0) offsets[0] = 0;
}

// K2: scatter node ids into per-molecule lists (order fixed by K3 sort)
__global__ __launch_bounds__(256) void k_scatter(const int* __restrict__ assign,
                                                 const int* __restrict__ offsets,
                                                 int* __restrict__ cursor,
                                                 int* __restrict__ list) {
    int i = blockIdx.x * blockDim.x + threadIdx.x;
    if (i >= N_NODE) return;
    int m = assign[i];
    int p = atomicAdd(&cursor[m], 1);
    list[offsets[m] + p] = i;
}

// K3: sort each molecule's node list (<=49 elements) by rank for determinism
__global__ __launch_bounds__(64) void k_sort(const int* __restrict__ offsets,
                                             int* __restrict__ list) {
    __shared__ int s[64];
    int m = blockIdx.x;
    int off = offsets[m];
    int cnt = offsets[m + 1] - off;   // actual <= 49
    int t = threadIdx.x;
    int v = (t < cnt) ? list[off + t] : 0x7fffffff;
    s[t] = v;
    __syncthreads();
    if (t < cnt) {
        int rank = 0;
        for (int j = 0; j < cnt; ++j) rank += (s[j] < v);
        list[off + rank] = v;
    }
}

// K4: node GEMM  out[N,128] = act( A @ W.T + b ),  A = node (K=128) or node||pos (K=192)
// BM=64 nodes, BN=128 outs, BK=16; 256 threads, 4x8 register micro-tile.
template <int K, int ACT>
__global__ __launch_bounds__(256) void k_gemm_nodes(const float* __restrict__ node,
                                                    const float* __restrict__ pos,
                                                    const float* __restrict__ W,
                                                    const float* __restrict__ b,
                                                    float* __restrict__ out) {
    __shared__ float sA[16][65];    // [k][node]
    __shared__ float sW[16][129];   // [k][c]
    int n0 = blockIdx.x * 64;
    int t = threadIdx.x;
    int tx = t & 15;   // channel group: c = tx*8 .. tx*8+7
    int ty = t >> 4;   // node group:   n = ty*4 .. ty*4+3
    float acc[4][8] = {};
    for (int k0 = 0; k0 < K; k0 += 16) {
        // stage A chunk (64x16): idx -> kk inner for coalesced global reads
        for (int idx = t; idx < 64 * 16; idx += 256) {
            int kk = idx & 15, n = idx >> 4;
            int gn = n0 + n, gk = k0 + kk;
            float v = 0.f;
            if (gn < N_NODE) {
                v = (gk < C_DIM) ? node[(size_t)gn * C_DIM + gk]
                                 : pos[(size_t)gn * P_DIM + (gk - C_DIM)];
            }
            sA[kk][n] = v;
        }
        // stage W chunk (128x16)
        for (int idx = t; idx < 128 * 16; idx += 256) {
            int kk = idx & 15, c = idx >> 4;
            sW[kk][c] = W[(size_t)c * K + (k0 + kk)];
        }
        __syncthreads();
#pragma unroll
        for (int kk = 0; kk < 16; ++kk) {
            float av[4], wv[8];
#pragma unroll
            for (int i2 = 0; i2 < 4; ++i2) av[i2] = sA[kk][ty * 4 + i2];
#pragma unroll
            for (int j = 0; j < 8; ++j) wv[j] = sW[kk][tx * 8 + j];
#pragma unroll
            for (int i2 = 0; i2 < 4; ++i2)
#pragma unroll
                for (int j = 0; j < 8; ++j) acc[i2][j] += av[i2] * wv[j];
        }
        __syncthreads();
    }
    for (int i2 = 0; i2 < 4; ++i2) {
        int gn = n0 + ty * 4 + i2;
        if (gn >= N_NODE) continue;
        for (int j = 0; j < 8; ++j) {
            int c = tx * 8 + j;
            float v = acc[i2][j] + b[c];
            if (ACT == 1) v = (v > 0.f) ? v : 0.01f * v;
            out[(size_t)gn * 128 + c] = v;
        }
    }
}

// K5: mol0 = segment-sum of mapped rows (block per molecule, thread per channel)
__global__ __launch_bounds__(128) void k_mol0(const float* __restrict__ mapped,
                                              const int* __restrict__ offsets,
                                              const int* __restrict__ list,
                                              float* __restrict__ mol) {
    int m = blockIdx.x, c = threadIdx.x;
    int off = offsets[m], end = offsets[m + 1];
    float acc = 0.f;
    for (int p = off; p < end; ++p) {
        int i = list[p];
        acc += mapped[(size_t)i * 128 + c];
    }
    mol[m * 128 + c] = acc;
}

// K6: one RADIUS step, block per molecule, 128 threads.
//   a_i = leaky( mol.alignW[0:128] + pos_i.alignW[128:192] + node_i.alignW[192:320] + b )
//   w = softmax(a), ctx = elu(sum w_i h_i), mol = relu(GRU(ctx, mol))
__global__ __launch_bounds__(128) void k_radius(const float* __restrict__ node,
                                                const float* __restrict__ pos,
                                                const float* __restrict__ h,
                                                const float* __restrict__ alignW,
                                                const float* __restrict__ alignb,
                                                const float* __restrict__ Wih,
                                                const float* __restrict__ Whh,
                                                const float* __restrict__ bih,
                                                const float* __restrict__ bhh,
                                                const int* __restrict__ offsets,
                                                const int* __restrict__ list,
                                                float* __restrict__ mol) {
    __shared__ float s_mol[128];
    __shared__ float s_ctx[128];
    __shared__ float s_a[64];
    __shared__ float s_red[128];
    int m = blockIdx.x;
    int t = threadIdx.x;
    int off = offsets[m], cnt = offsets[m + 1] - off;   // cnt <= 49

    float molc = mol[m * 128 + t];
    s_mol[t] = molc;

    // dot_mol = mol . alignW[0:128]  (same for every node in this molecule)
    s_red[t] = molc * alignW[t];
    __syncthreads();
    for (int d = 64; d > 0; d >>= 1) {
        if (t < d) s_red[t] += s_red[t + d];
        __syncthreads();
    }
    float dot_mol = s_red[0] + alignb[0];

    // per-node score: 2 waves, each wave handles alternate nodes, 64-lane dot
    int wave = t >> 6, lane = t & 63;
    for (int p = wave; p < cnt; p += 2) {
        int i = list[off + p];
        float v = pos[(size_t)i * P_DIM + lane] * alignW[128 + lane]
                + node[(size_t)i * C_DIM + lane] * alignW[192 + lane]
                + node[(size_t)i * C_DIM + 64 + lane] * alignW[256 + lane];
        for (int d = 32; d > 0; d >>= 1) v += __shfl_down(v, d);
        if (lane == 0) {
            float a = dot_mol + v;
            s_a[p] = (a > 0.f) ? a : 0.01f * a;
        }
    }
    __syncthreads();

    // softmax over the segment (wave 0 only; cnt <= 64)
    if (t < 64) {
        float x = (t < cnt) ? s_a[t] : -1e30f;
        float mx = x;
        for (int d = 32; d > 0; d >>= 1) mx = fmaxf(mx, __shfl_xor(mx, d));
        float e = (t < cnt) ? __expf(x - mx) : 0.f;
        float sm = e;
        for (int d = 32; d > 0; d >>= 1) sm += __shfl_xor(sm, d);
        if (t < cnt) s_a[t] = e / sm;
    }
    __syncthreads();

    // context channel t = sum_i w_i * h[i, t], then ELU
    float ctx = 0.f;
    for (int p = 0; p < cnt; ++p) {
        int i = list[off + p];
        ctx += s_a[p] * h[(size_t)i * 128 + t];
    }
    ctx = (ctx > 0.f) ? ctx : (__expf(ctx) - 1.f);
    s_ctx[t] = ctx;
    __syncthreads();

    // GRU cell: thread t owns gate channels (t, 128+t, 256+t)
    float gi_r = bih[t],       gh_r = bhh[t];
    float gi_z = bih[128 + t], gh_z = bhh[128 + t];
    float gi_n = bih[256 + t], gh_n = bhh[256 + t];
    for (int k = 0; k < 128; ++k) {
        float cx = s_ctx[k], hm = s_mol[k];
        gi_r += cx * Wih[(size_t)t * 128 + k];
        gh_r += hm * Whh[(size_t)t * 128 + k];
        gi_z += cx * Wih[(size_t)(128 + t) * 128 + k];
        gh_z += hm * Whh[(size_t)(128 + t) * 128 + k];
        gi_n += cx * Wih[(size_t)(256 + t) * 128 + k];
        gh_n += hm * Whh[(size_t)(256 + t) * 128 + k];
    }
    float r = 1.f / (1.f + __expf(-(gi_r + gh_r)));
    float z = 1.f / (1.f + __expf(-(gi_z + gh_z)));
    float n = tanhf(gi_n + r * gh_n);
    float nm = (1.f - z) * n + z * molc;
    mol[m * 128 + t] = fmaxf(nm, 0.f);
}

extern "C" void kernel_launch(void* const* d_in, const int* in_sizes, int n_in,
                              void* d_out, int out_size, void* d_ws, size_t ws_size,
                              hipStream_t stream) {
    const float* node   = (const float*)d_in[0];
    const float* pos    = (const float*)d_in[1];
    const float* mat    = (const float*)d_in[2];
    // d_in[3] = mask (unused: implied by mat)
    const float* map_W  = (const float*)d_in[4];
    const float* map_b  = (const float*)d_in[5];
    const float* att_W  = (const float*)d_in[6];
    const float* att_b  = (const float*)d_in[7];
    const float* alignW = (const float*)d_in[8];
    const float* alignb = (const float*)d_in[9];
    const float* gWih   = (const float*)d_in[10];
    const float* gWhh   = (const float*)d_in[11];
    const float* gbih   = (const float*)d_in[12];
    const float* gbhh   = (const float*)d_in[13];
    float* mol = (float*)d_out;   // [1024,128] — used as the running mol buffer

    // workspace carve-up (256B aligned)
    size_t o = 0;
    auto alloc = [&](size_t bytes) { size_t r = o; o += (bytes + 255) & ~(size_t)255; return r; };
    char* ws = (char*)d_ws;
    int*   assign  = (int*)(ws + alloc((size_t)N_NODE * 4));
    int*   counts  = (int*)(ws + alloc((size_t)N_MOL * 4));
    int*   cursor  = (int*)(ws + alloc((size_t)N_MOL * 4));
    int*   offsets = (int*)(ws + alloc((size_t)(N_MOL + 1) * 4));
    int*   list    = (int*)(ws + alloc((size_t)N_NODE * 4));
    float* mapped  = (float*)(ws + alloc((size_t)N_NODE * 128 * 4));
    float* hbuf    = (float*)(ws + alloc((size_t)N_NODE * 128 * 4));

    // counts and cursor are adjacent 4KB-aligned blocks -> one memset
    hipMemsetAsync(counts, 0, 2 * ((N_MOL * 4 + 255) & ~(size_t)255), stream);

    int nblk = (N_NODE + 255) / 256;
    k_assign<<<nblk, 256, 0, stream>>>(mat, assign, counts);
    k_scan<<<1, 1024, 0, stream>>>(counts, offsets);
    k_scatter<<<nblk, 256, 0, stream>>>(assign, offsets, cursor, list);
    k_sort<<<N_MOL, 64, 0, stream>>>(offsets, list);

    int gblk = (N_NODE + 63) / 64;
    k_gemm_nodes<128, 1><<<gblk, 256, 0, stream>>>(node, pos, map_W, map_b, mapped);
    k_gemm_nodes<192, 0><<<gblk, 256, 0, stream>>>(node, pos, att_W, att_b, hbuf);

    k_mol0<<<N_MOL, 128, 0, stream>>>(mapped, offsets, list, mol);

    for (int r = 0; r < 2; ++r) {
        k_radius<<<N_MOL, 128, 0, stream>>>(node, pos, hbuf, alignW, alignb,
                                            gWih, gWhh, gbih, gbhh,
                                            offsets, list, mol);
    }
}

// Round 2
// 471.818 us; speedup vs baseline: 1.4759x; 1.4759x over previous
//
#include <hip/hip_runtime.h>
#include <hip/hip_bf16.h>
#include <math.h>

#define N_NODE 50000
#define N_MOL  1024
#define C_DIM  128
#define P_DIM  64
#define M_DIM  128

// ---------------------------------------------------------------------------
// K0: derive per-node molecule assignment from the one-hot matrix.
// Full flat scan, float4-vectorized, grid-stride: 205 MB streamed once at
// HBM/L3 bandwidth. Exactly one nonzero per column -> unique writer per i.
__global__ __launch_bounds__(256) void k_assign(const float4* __restrict__ mat4,
                                                int* __restrict__ assign,
                                                int* __restrict__ counts) {
    const int total4 = (N_MOL * N_NODE) / 4;   // 12.8M float4s
    int stride = gridDim.x * blockDim.x;
    for (int j = blockIdx.x * blockDim.x + threadIdx.x; j < total4; j += stride) {
        float4 v = mat4[j];
        if (v.x > 0.5f || v.y > 0.5f || v.z > 0.5f || v.w > 0.5f) {
            int base = j * 4;
            float f[4] = {v.x, v.y, v.z, v.w};
#pragma unroll
            for (int c = 0; c < 4; ++c) {
                if (f[c] > 0.5f) {
                    int idx = base + c;
                    int m = idx / N_NODE;          // rare path: magic-mul div
                    int i = idx - m * N_NODE;
                    assign[i] = m;
                    atomicAdd(&counts[m], 1);
                }
            }
        }
    }
}

// K1: exclusive prefix sum of counts -> offsets (single block, 1024 threads)
__global__ __launch_bounds__(1024) void k_scan(const int* __restrict__ counts,
                                               int* __restrict__ offsets) {
    __shared__ int s[N_MOL];
    int t = threadIdx.x;
    s[t] = counts[t];
    __syncthreads();
    for (int d = 1; d < N_MOL; d <<= 1) {
        int v = (t >= d) ? s[t - d] : 0;
        __syncthreads();
        s[t] += v;
        __syncthreads();
    }
    offsets[t + 1] = s[t];
    if (t == 0) offsets[0] = 0;
}

// K2: scatter node ids into per-molecule lists (order fixed by K3 sort)
__global__ __launch_bounds__(256) void k_scatter(const int* __restrict__ assign,
                                                 const int* __restrict__ offsets,
                                                 int* __restrict__ cursor,
                                                 int* __restrict__ list) {
    int i = blockIdx.x * blockDim.x + threadIdx.x;
    if (i >= N_NODE) return;
    int m = assign[i];
    int p = atomicAdd(&cursor[m], 1);
    list[offsets[m] + p] = i;
}

// K3: sort each molecule's node list (<=49 elements) by rank for determinism
__global__ __launch_bounds__(64) void k_sort(const int* __restrict__ offsets,
                                             int* __restrict__ list) {
    __shared__ int s[64];
    int m = blockIdx.x;
    int off = offsets[m];
    int cnt = offsets[m + 1] - off;   // actual <= 49
    int t = threadIdx.x;
    int v = (t < cnt) ? list[off + t] : 0x7fffffff;
    s[t] = v;
    __syncthreads();
    if (t < cnt) {
        int rank = 0;
        for (int j = 0; j < cnt; ++j) rank += (s[j] < v);
        list[off + rank] = v;
    }
}

// K4: node GEMM  out[N,128] = act( A @ W.T + b ),  A = node (K=128) or node||pos (K=192)
// BM=64 nodes, BN=128 outs, BK=16; 256 threads, 4x8 register micro-tile.
template <int K, int ACT>
__global__ __launch_bounds__(256) void k_gemm_nodes(const float* __restrict__ node,
                                                    const float* __restrict__ pos,
                                                    const float* __restrict__ W,
                                                    const float* __restrict__ b,
                                                    float* __restrict__ out) {
    __shared__ float sA[16][65];    // [k][node]
    __shared__ float sW[16][129];   // [k][c]
    int n0 = blockIdx.x * 64;
    int t = threadIdx.x;
    int tx = t & 15;   // channel group: c = tx*8 .. tx*8+7
    int ty = t >> 4;   // node group:   n = ty*4 .. ty*4+3
    float acc[4][8] = {};
    for (int k0 = 0; k0 < K; k0 += 16) {
        // stage A chunk (64x16): idx -> kk inner for coalesced global reads
        for (int idx = t; idx < 64 * 16; idx += 256) {
            int kk = idx & 15, n = idx >> 4;
            int gn = n0 + n, gk = k0 + kk;
            float v = 0.f;
            if (gn < N_NODE) {
                v = (gk < C_DIM) ? node[(size_t)gn * C_DIM + gk]
                                 : pos[(size_t)gn * P_DIM + (gk - C_DIM)];
            }
            sA[kk][n] = v;
        }
        // stage W chunk (128x16)
        for (int idx = t; idx < 128 * 16; idx += 256) {
            int kk = idx & 15, c = idx >> 4;
            sW[kk][c] = W[(size_t)c * K + (k0 + kk)];
        }
        __syncthreads();
#pragma unroll
        for (int kk = 0; kk < 16; ++kk) {
            float av[4], wv[8];
#pragma unroll
            for (int i2 = 0; i2 < 4; ++i2) av[i2] = sA[kk][ty * 4 + i2];
#pragma unroll
            for (int j = 0; j < 8; ++j) wv[j] = sW[kk][tx * 8 + j];
#pragma unroll
            for (int i2 = 0; i2 < 4; ++i2)
#pragma unroll
                for (int j = 0; j < 8; ++j) acc[i2][j] += av[i2] * wv[j];
        }
        __syncthreads();
    }
    for (int i2 = 0; i2 < 4; ++i2) {
        int gn = n0 + ty * 4 + i2;
        if (gn >= N_NODE) continue;
        for (int j = 0; j < 8; ++j) {
            int c = tx * 8 + j;
            float v = acc[i2][j] + b[c];
            if (ACT == 1) v = (v > 0.f) ? v : 0.01f * v;
            out[(size_t)gn * 128 + c] = v;
        }
    }
}

// K5: mol0 = segment-sum of mapped rows (block per molecule, thread per channel)
__global__ __launch_bounds__(128) void k_mol0(const float* __restrict__ mapped,
                                              const int* __restrict__ offsets,
                                              const int* __restrict__ list,
                                              float* __restrict__ mol) {
    int m = blockIdx.x, c = threadIdx.x;
    int off = offsets[m], end = offsets[m + 1];
    float acc = 0.f;
    for (int p = off; p < end; ++p) {
        int i = list[p];
        acc += mapped[(size_t)i * 128 + c];
    }
    mol[m * 128 + c] = acc;
}

// K6: one RADIUS step, block per molecule, 128 threads.
//   a_i = leaky( mol.alignW[0:128] + pos_i.alignW[128:192] + node_i.alignW[192:320] + b )
//   w = softmax(a), ctx = elu(sum w_i h_i), mol = relu(GRU(ctx, mol))
__global__ __launch_bounds__(128) void k_radius(const float* __restrict__ node,
                                                const float* __restrict__ pos,
                                                const float* __restrict__ h,
                                                const float* __restrict__ alignW,
                                                const float* __restrict__ alignb,
                                                const float* __restrict__ Wih,
                                                const float* __restrict__ Whh,
                                                const float* __restrict__ bih,
                                                const float* __restrict__ bhh,
                                                const int* __restrict__ offsets,
                                                const int* __restrict__ list,
                                                float* __restrict__ mol) {
    __shared__ float s_mol[128];
    __shared__ float s_ctx[128];
    __shared__ float s_a[64];
    __shared__ float s_red[128];
    int m = blockIdx.x;
    int t = threadIdx.x;
    int off = offsets[m], cnt = offsets[m + 1] - off;   // cnt <= 49

    float molc = mol[m * 128 + t];
    s_mol[t] = molc;

    // dot_mol = mol . alignW[0:128]  (same for every node in this molecule)
    s_red[t] = molc * alignW[t];
    __syncthreads();
    for (int d = 64; d > 0; d >>= 1) {
        if (t < d) s_red[t] += s_red[t + d];
        __syncthreads();
    }
    float dot_mol = s_red[0] + alignb[0];

    // per-node score: 2 waves, each wave handles alternate nodes, 64-lane dot
    int wave = t >> 6, lane = t & 63;
    for (int p = wave; p < cnt; p += 2) {
        int i = list[off + p];
        float v = pos[(size_t)i * P_DIM + lane] * alignW[128 + lane]
                + node[(size_t)i * C_DIM + lane] * alignW[192 + lane]
                + node[(size_t)i * C_DIM + 64 + lane] * alignW[256 + lane];
        for (int d = 32; d > 0; d >>= 1) v += __shfl_down(v, d);
        if (lane == 0) {
            float a = dot_mol + v;
            s_a[p] = (a > 0.f) ? a : 0.01f * a;
        }
    }
    __syncthreads();

    // softmax over the segment (wave 0 only; cnt <= 64)
    if (t < 64) {
        float x = (t < cnt) ? s_a[t] : -1e30f;
        float mx = x;
        for (int d = 32; d > 0; d >>= 1) mx = fmaxf(mx, __shfl_xor(mx, d));
        float e = (t < cnt) ? __expf(x - mx) : 0.f;
        float sm = e;
        for (int d = 32; d > 0; d >>= 1) sm += __shfl_xor(sm, d);
        if (t < cnt) s_a[t] = e / sm;
    }
    __syncthreads();

    // context channel t = sum_i w_i * h[i, t], then ELU
    float ctx = 0.f;
    for (int p = 0; p < cnt; ++p) {
        int i = list[off + p];
        ctx += s_a[p] * h[(size_t)i * 128 + t];
    }
    ctx = (ctx > 0.f) ? ctx : (__expf(ctx) - 1.f);
    s_ctx[t] = ctx;
    __syncthreads();

    // GRU cell: thread t owns gate channels (t, 128+t, 256+t)
    float gi_r = bih[t],       gh_r = bhh[t];
    float gi_z = bih[128 + t], gh_z = bhh[128 + t];
    float gi_n = bih[256 + t], gh_n = bhh[256 + t];
    for (int k = 0; k < 128; ++k) {
        float cx = s_ctx[k], hm = s_mol[k];
        gi_r += cx * Wih[(size_t)t * 128 + k];
        gh_r += hm * Whh[(size_t)t * 128 + k];
        gi_z += cx * Wih[(size_t)(128 + t) * 128 + k];
        gh_z += hm * Whh[(size_t)(128 + t) * 128 + k];
        gi_n += cx * Wih[(size_t)(256 + t) * 128 + k];
        gh_n += hm * Whh[(size_t)(256 + t) * 128 + k];
    }
    float r = 1.f / (1.f + __expf(-(gi_r + gh_r)));
    float z = 1.f / (1.f + __expf(-(gi_z + gh_z)));
    float n = tanhf(gi_n + r * gh_n);
    float nm = (1.f - z) * n + z * molc;
    mol[m * 128 + t] = fmaxf(nm, 0.f);
}

extern "C" void kernel_launch(void* const* d_in, const int* in_sizes, int n_in,
                              void* d_out, int out_size, void* d_ws, size_t ws_size,
                              hipStream_t stream) {
    const float* node   = (const float*)d_in[0];
    const float* pos    = (const float*)d_in[1];
    const float* mat    = (const float*)d_in[2];
    // d_in[3] = mask (unused: implied by mat)
    const float* map_W  = (const float*)d_in[4];
    const float* map_b  = (const float*)d_in[5];
    const float* att_W  = (const float*)d_in[6];
    const float* att_b  = (const float*)d_in[7];
    const float* alignW = (const float*)d_in[8];
    const float* alignb = (const float*)d_in[9];
    const float* gWih   = (const float*)d_in[10];
    const float* gWhh   = (const float*)d_in[11];
    const float* gbih   = (const float*)d_in[12];
    const float* gbhh   = (const float*)d_in[13];
    float* mol = (float*)d_out;   // [1024,128] — used as the running mol buffer

    // workspace carve-up (256B aligned)
    size_t o = 0;
    auto alloc = [&](size_t bytes) { size_t r = o; o += (bytes + 255) & ~(size_t)255; return r; };
    char* ws = (char*)d_ws;
    int*   assign  = (int*)(ws + alloc((size_t)N_NODE * 4));
    int*   counts  = (int*)(ws + alloc((size_t)N_MOL * 4));
    int*   cursor  = (int*)(ws + alloc((size_t)N_MOL * 4));
    int*   offsets = (int*)(ws + alloc((size_t)(N_MOL + 1) * 4));
    int*   list    = (int*)(ws + alloc((size_t)N_NODE * 4));
    float* mapped  = (float*)(ws + alloc((size_t)N_NODE * 128 * 4));
    float* hbuf    = (float*)(ws + alloc((size_t)N_NODE * 128 * 4));

    // counts and cursor are adjacent 256B-aligned blocks -> one memset
    hipMemsetAsync(counts, 0, 2 * ((N_MOL * 4 + 255) & ~(size_t)255), stream);

    k_assign<<<2048, 256, 0, stream>>>((const float4*)mat, assign, counts);
    k_scan<<<1, 1024, 0, stream>>>(counts, offsets);
    int nblk = (N_NODE + 255) / 256;
    k_scatter<<<nblk, 256, 0, stream>>>(assign, offsets, cursor, list);
    k_sort<<<N_MOL, 64, 0, stream>>>(offsets, list);

    int gblk = (N_NODE + 63) / 64;
    k_gemm_nodes<128, 1><<<gblk, 256, 0, stream>>>(node, pos, map_W, map_b, mapped);
    k_gemm_nodes<192, 0><<<gblk, 256, 0, stream>>>(node, pos, att_W, att_b, hbuf);

    k_mol0<<<N_MOL, 128, 0, stream>>>(mapped, offsets, list, mol);

    for (int r = 0; r < 2; ++r) {
        k_radius<<<N_MOL, 128, 0, stream>>>(node, pos, hbuf, alignW, alignb,
                                            gWih, gWhh, gbih, gbhh,
                                            offsets, list, mol);
    }
}

// Round 3
// 305.729 us; speedup vs baseline: 2.2777x; 1.5433x over previous
//
#include <hip/hip_runtime.h>
#include <hip/hip_bf16.h>
#include <math.h>

#define N_NODE 50000
#define N_MOL  1024
#define C_DIM  128
#define P_DIM  64
#define M_DIM  128

typedef __attribute__((ext_vector_type(8))) short bf16x8;
typedef __attribute__((ext_vector_type(4))) float f32x4;

static __device__ __forceinline__ short f2bf(float x) {
    __hip_bfloat16 h = __float2bfloat16(x);
    return *reinterpret_cast<short*>(&h);
}

// ---------------------------------------------------------------------------
// K0a: guess assign[i] = i % N_MOL and verify with ONE scattered read/column.
// If any column's guess is wrong, set fail flag (full scan takes over).
__global__ __launch_bounds__(256) void k_guess(const float* __restrict__ mat,
                                               int* __restrict__ assign,
                                               int* __restrict__ fail) {
    int i = blockIdx.x * blockDim.x + threadIdx.x;
    if (i >= N_NODE) return;
    int m = i & (N_MOL - 1);
    assign[i] = m;
    if (!(mat[(size_t)m * N_NODE + i] > 0.5f)) atomicAdd(fail, 1);
}

// K0b: full fallback scan (no-op when fail==0). Float4 grid-stride stream.
__global__ __launch_bounds__(256) void k_assign_full(const float4* __restrict__ mat4,
                                                     int* __restrict__ assign,
                                                     const int* __restrict__ fail) {
    if (*fail == 0) return;
    const int total4 = (N_MOL * N_NODE) / 4;
    int stride = gridDim.x * blockDim.x;
    for (int j = blockIdx.x * blockDim.x + threadIdx.x; j < total4; j += stride) {
        float4 v = mat4[j];
        if (v.x > 0.5f || v.y > 0.5f || v.z > 0.5f || v.w > 0.5f) {
            int base = j * 4;
            float f[4] = {v.x, v.y, v.z, v.w};
#pragma unroll
            for (int c = 0; c < 4; ++c) {
                if (f[c] > 0.5f) {
                    int idx = base + c;
                    int m = idx / N_NODE;
                    int i = idx - m * N_NODE;
                    assign[i] = m;
                }
            }
        }
    }
}

// K0c: counts from final assign
__global__ __launch_bounds__(256) void k_count(const int* __restrict__ assign,
                                               int* __restrict__ counts) {
    int i = blockIdx.x * blockDim.x + threadIdx.x;
    if (i >= N_NODE) return;
    atomicAdd(&counts[assign[i]], 1);
}

// K1: exclusive prefix sum of counts -> offsets (single block, 1024 threads)
__global__ __launch_bounds__(1024) void k_scan(const int* __restrict__ counts,
                                               int* __restrict__ offsets) {
    __shared__ int s[N_MOL];
    int t = threadIdx.x;
    s[t] = counts[t];
    __syncthreads();
    for (int d = 1; d < N_MOL; d <<= 1) {
        int v = (t >= d) ? s[t - d] : 0;
        __syncthreads();
        s[t] += v;
        __syncthreads();
    }
    offsets[t + 1] = s[t];
    if (t == 0) offsets[0] = 0;
}

// K2: scatter node ids into per-molecule lists (order fixed by K3 sort)
__global__ __launch_bounds__(256) void k_scatter(const int* __restrict__ assign,
                                                 const int* __restrict__ offsets,
                                                 int* __restrict__ cursor,
                                                 int* __restrict__ list) {
    int i = blockIdx.x * blockDim.x + threadIdx.x;
    if (i >= N_NODE) return;
    int m = assign[i];
    int p = atomicAdd(&cursor[m], 1);
    list[offsets[m] + p] = i;
}

// K3: sort each molecule's node list (<=49 elements) by rank for determinism
__global__ __launch_bounds__(64) void k_sort(const int* __restrict__ offsets,
                                             int* __restrict__ list) {
    __shared__ int s[64];
    int m = blockIdx.x;
    int off = offsets[m];
    int cnt = offsets[m + 1] - off;
    int t = threadIdx.x;
    int v = (t < cnt) ? list[off + t] : 0x7fffffff;
    s[t] = v;
    __syncthreads();
    if (t < cnt) {
        int rank = 0;
        for (int j = 0; j < cnt; ++j) rank += (s[j] < v);
        list[off + rank] = v;
    }
}

// K4a: combined weight matrix -> bf16 [256 rows x 192 k], row-major.
// rows 0..127 = map_W (K=128, zero-padded to 192); rows 128..255 = att_W.
__global__ __launch_bounds__(256) void k_prep_b(const float* __restrict__ map_W,
                                                const float* __restrict__ att_W,
                                                short* __restrict__ Bbf) {
    int idx = blockIdx.x * blockDim.x + threadIdx.x;
    if (idx >= 256 * 192) return;
    int r = idx / 192, k = idx - r * 192;
    float v = 0.f;
    if (r < 128) { if (k < 128) v = map_W[r * 128 + k]; }
    else v = att_W[(size_t)(r - 128) * 192 + k];
    Bbf[idx] = f2bf(v);
}

// K4b: fused MFMA GEMM: C[50000 x 256] = (node||pos) @ [map_W pad | att_W]^T
// cols 0..127 -> leaky+bias -> mapped ; cols 128..255 -> +bias -> hbuf.
// Block: 64 nodes x 256 cols, 256 threads (2x2 waves, each 32 rows x 128 cols).
// A staged fp32->bf16 in LDS, row stride 224 (448B = 112 dwords: bank-uniform).
__global__ __launch_bounds__(256) void k_gemm_fused(const float* __restrict__ node,
                                                    const float* __restrict__ pos,
                                                    const short* __restrict__ Bbf,
                                                    const float* __restrict__ map_b,
                                                    const float* __restrict__ att_b,
                                                    float* __restrict__ mapped,
                                                    float* __restrict__ hbuf) {
    __shared__ short sA[64 * 224];
    int t = threadIdx.x;
    int n0 = blockIdx.x * 64;

    // stage A tile: 64 rows x 192 k, fp32 -> bf16, float4-vectorized
    for (int idx = t; idx < 64 * 48; idx += 256) {
        int row = idx / 48;
        int c4 = idx - row * 48;        // float4 index within row (0..47)
        int gn = n0 + row;
        float4 v = make_float4(0.f, 0.f, 0.f, 0.f);
        if (gn < N_NODE) {
            if (c4 < 32) v = *(const float4*)&node[(size_t)gn * C_DIM + c4 * 4];
            else         v = *(const float4*)&pos[(size_t)gn * P_DIM + (c4 - 32) * 4];
        }
        ushort4 u;
        u.x = (unsigned short)f2bf(v.x);
        u.y = (unsigned short)f2bf(v.y);
        u.z = (unsigned short)f2bf(v.z);
        u.w = (unsigned short)f2bf(v.w);
        *(ushort4*)&sA[row * 224 + c4 * 4] = u;
    }
    __syncthreads();

    int wid = t >> 6, lane = t & 63;
    int wr = wid >> 1, wc = wid & 1;
    int lrow = lane & 15, lk = (lane >> 4) * 8;

    // A fragments: lane holds A[row = base+(lane&15)][k = k0 + (lane>>4)*8 + 0..7]
    bf16x8 a[2][6];
#pragma unroll
    for (int mt = 0; mt < 2; ++mt)
#pragma unroll
        for (int k = 0; k < 6; ++k)
            a[mt][k] = *(const bf16x8*)&sA[(wr * 32 + mt * 16 + lrow) * 224 + k * 32 + lk];

    f32x4 acc[2][8] = {};
#pragma unroll
    for (int ct = 0; ct < 8; ++ct) {
        int c0 = wc * 128 + ct * 16;
        bf16x8 b[6];
#pragma unroll
        for (int k = 0; k < 6; ++k)
            b[k] = *(const bf16x8*)&Bbf[(size_t)(c0 + lrow) * 192 + k * 32 + lk];
#pragma unroll
        for (int mt = 0; mt < 2; ++mt)
#pragma unroll
            for (int k = 0; k < 6; ++k)
                acc[mt][ct] = __builtin_amdgcn_mfma_f32_16x16x32_bf16(
                    a[mt][k], b[k], acc[mt][ct], 0, 0, 0);
    }

    // epilogue: C/D layout col = lane&15, row = (lane>>4)*4 + reg
#pragma unroll
    for (int ct = 0; ct < 8; ++ct) {
        int c = wc * 128 + ct * 16 + lrow;
        float bias = (c < 128) ? map_b[c] : att_b[c - 128];
#pragma unroll
        for (int mt = 0; mt < 2; ++mt) {
#pragma unroll
            for (int r = 0; r < 4; ++r) {
                int gn = n0 + wr * 32 + mt * 16 + (lane >> 4) * 4 + r;
                if (gn >= N_NODE) continue;
                float v = acc[mt][ct][r] + bias;
                if (c < 128) {
                    v = (v > 0.f) ? v : 0.01f * v;
                    mapped[(size_t)gn * 128 + c] = v;
                } else {
                    hbuf[(size_t)gn * 128 + (c - 128)] = v;
                }
            }
        }
    }
}

// K5: mol0 = segment-sum of mapped rows (block per molecule, thread per channel)
__global__ __launch_bounds__(128) void k_mol0(const float* __restrict__ mapped,
                                              const int* __restrict__ offsets,
                                              const int* __restrict__ list,
                                              float* __restrict__ mol) {
    int m = blockIdx.x, c = threadIdx.x;
    int off = offsets[m], end = offsets[m + 1];
    float acc = 0.f;
    for (int p = off; p < end; ++p) {
        int i = list[p];
        acc += mapped[(size_t)i * 128 + c];
    }
    mol[m * 128 + c] = acc;
}

// K6: one RADIUS step, block per molecule, 128 threads.
__global__ __launch_bounds__(128) void k_radius(const float* __restrict__ node,
                                                const float* __restrict__ pos,
                                                const float* __restrict__ h,
                                                const float* __restrict__ alignW,
                                                const float* __restrict__ alignb,
                                                const float* __restrict__ Wih,
                                                const float* __restrict__ Whh,
                                                const float* __restrict__ bih,
                                                const float* __restrict__ bhh,
                                                const int* __restrict__ offsets,
                                                const int* __restrict__ list,
                                                float* __restrict__ mol) {
    __shared__ float s_mol[128];
    __shared__ float s_ctx[128];
    __shared__ float s_a[64];
    __shared__ float s_red[128];
    int m = blockIdx.x;
    int t = threadIdx.x;
    int off = offsets[m], cnt = offsets[m + 1] - off;   // cnt <= 49

    float molc = mol[m * 128 + t];
    s_mol[t] = molc;

    s_red[t] = molc * alignW[t];
    __syncthreads();
    for (int d = 64; d > 0; d >>= 1) {
        if (t < d) s_red[t] += s_red[t + d];
        __syncthreads();
    }
    float dot_mol = s_red[0] + alignb[0];

    int wave = t >> 6, lane = t & 63;
    for (int p = wave; p < cnt; p += 2) {
        int i = list[off + p];
        float v = pos[(size_t)i * P_DIM + lane] * alignW[128 + lane]
                + node[(size_t)i * C_DIM + lane] * alignW[192 + lane]
                + node[(size_t)i * C_DIM + 64 + lane] * alignW[256 + lane];
        for (int d = 32; d > 0; d >>= 1) v += __shfl_down(v, d);
        if (lane == 0) {
            float a = dot_mol + v;
            s_a[p] = (a > 0.f) ? a : 0.01f * a;
        }
    }
    __syncthreads();

    if (t < 64) {
        float x = (t < cnt) ? s_a[t] : -1e30f;
        float mx = x;
        for (int d = 32; d > 0; d >>= 1) mx = fmaxf(mx, __shfl_xor(mx, d));
        float e = (t < cnt) ? __expf(x - mx) : 0.f;
        float sm = e;
        for (int d = 32; d > 0; d >>= 1) sm += __shfl_xor(sm, d);
        if (t < cnt) s_a[t] = e / sm;
    }
    __syncthreads();

    float ctx = 0.f;
    for (int p = 0; p < cnt; ++p) {
        int i = list[off + p];
        ctx += s_a[p] * h[(size_t)i * 128 + t];
    }
    ctx = (ctx > 0.f) ? ctx : (__expf(ctx) - 1.f);
    s_ctx[t] = ctx;
    __syncthreads();

    float gi_r = bih[t],       gh_r = bhh[t];
    float gi_z = bih[128 + t], gh_z = bhh[128 + t];
    float gi_n = bih[256 + t], gh_n = bhh[256 + t];
    for (int k = 0; k < 128; ++k) {
        float cx = s_ctx[k], hm = s_mol[k];
        gi_r += cx * Wih[(size_t)t * 128 + k];
        gh_r += hm * Whh[(size_t)t * 128 + k];
        gi_z += cx * Wih[(size_t)(128 + t) * 128 + k];
        gh_z += hm * Whh[(size_t)(128 + t) * 128 + k];
        gi_n += cx * Wih[(size_t)(256 + t) * 128 + k];
        gh_n += hm * Whh[(size_t)(256 + t) * 128 + k];
    }
    float r = 1.f / (1.f + __expf(-(gi_r + gh_r)));
    float z = 1.f / (1.f + __expf(-(gi_z + gh_z)));
    float n = tanhf(gi_n + r * gh_n);
    float nm = (1.f - z) * n + z * molc;
    mol[m * 128 + t] = fmaxf(nm, 0.f);
}

extern "C" void kernel_launch(void* const* d_in, const int* in_sizes, int n_in,
                              void* d_out, int out_size, void* d_ws, size_t ws_size,
                              hipStream_t stream) {
    const float* node   = (const float*)d_in[0];
    const float* pos    = (const float*)d_in[1];
    const float* mat    = (const float*)d_in[2];
    const float* map_W  = (const float*)d_in[4];
    const float* map_b  = (const float*)d_in[5];
    const float* att_W  = (const float*)d_in[6];
    const float* att_b  = (const float*)d_in[7];
    const float* alignW = (const float*)d_in[8];
    const float* alignb = (const float*)d_in[9];
    const float* gWih   = (const float*)d_in[10];
    const float* gWhh   = (const float*)d_in[11];
    const float* gbih   = (const float*)d_in[12];
    const float* gbhh   = (const float*)d_in[13];
    float* mol = (float*)d_out;   // [1024,128]

    size_t o = 0;
    auto alloc = [&](size_t bytes) { size_t r = o; o += (bytes + 255) & ~(size_t)255; return r; };
    char* ws = (char*)d_ws;
    int*   assign  = (int*)(ws + alloc((size_t)N_NODE * 4));
    size_t counts_off = alloc((size_t)N_MOL * 4);
    int*   counts  = (int*)(ws + counts_off);
    int*   cursor  = (int*)(ws + alloc((size_t)N_MOL * 4));
    int*   fail    = (int*)(ws + alloc(4));
    size_t fail_end = o;
    int*   offsets = (int*)(ws + alloc((size_t)(N_MOL + 1) * 4));
    int*   list    = (int*)(ws + alloc((size_t)N_NODE * 4));
    short* Bbf     = (short*)(ws + alloc((size_t)256 * 192 * 2));
    float* mapped  = (float*)(ws + alloc((size_t)N_NODE * 128 * 4));
    float* hbuf    = (float*)(ws + alloc((size_t)N_NODE * 128 * 4));

    // zero counts+cursor+fail in one memset (contiguous span)
    hipMemsetAsync(counts, 0, fail_end - counts_off, stream);

    int nblk = (N_NODE + 255) / 256;
    k_guess<<<nblk, 256, 0, stream>>>(mat, assign, fail);
    k_assign_full<<<2048, 256, 0, stream>>>((const float4*)mat, assign, fail);
    k_count<<<nblk, 256, 0, stream>>>(assign, counts);
    k_scan<<<1, 1024, 0, stream>>>(counts, offsets);
    k_scatter<<<nblk, 256, 0, stream>>>(assign, offsets, cursor, list);
    k_sort<<<N_MOL, 64, 0, stream>>>(offsets, list);

    k_prep_b<<<(256 * 192 + 255) / 256, 256, 0, stream>>>(map_W, att_W, Bbf);
    k_gemm_fused<<<(N_NODE + 63) / 64, 256, 0, stream>>>(node, pos, Bbf, map_b, att_b,
                                                         mapped, hbuf);

    k_mol0<<<N_MOL, 128, 0, stream>>>(mapped, offsets, list, mol);

    for (int r = 0; r < 2; ++r) {
        k_radius<<<N_MOL, 128, 0, stream>>>(node, pos, hbuf, alignW, alignb,
                                            gWih, gWhh, gbih, gbhh,
                                            offsets, list, mol);
    }
}

// Round 4
// 156.815 us; speedup vs baseline: 4.4406x; 1.9496x over previous
//
#include <hip/hip_runtime.h>
#include <hip/hip_bf16.h>
#include <math.h>

#define N_NODE 50000
#define N_MOL  1024
#define C_DIM  128
#define P_DIM  64
#define M_DIM  128

typedef __attribute__((ext_vector_type(8))) short bf16x8;
typedef __attribute__((ext_vector_type(4))) float f32x4;

static __device__ __forceinline__ short f2bf(float x) {
    __hip_bfloat16 h = __float2bfloat16(x);
    return *reinterpret_cast<short*>(&h);
}

// ---------------------------------------------------------------------------
// K_zero: zero counts[1024], cursor[1024], fail[1]  (replaces hipMemsetAsync,
// which showed up as a 117us fillBufferAligned dispatch in rocprof)
__global__ __launch_bounds__(256) void k_zero(int* __restrict__ counts,
                                              int* __restrict__ cursor,
                                              int* __restrict__ fail) {
    int t = blockIdx.x * blockDim.x + threadIdx.x;
    if (t < N_MOL) { counts[t] = 0; cursor[t] = 0; }
    if (t == 0) *fail = 0;
}

// K0a: guess assign[i] = i % N_MOL, verify with ONE scattered read/column,
// and count. If any guess is wrong, flag -> fallback path fixes everything.
__global__ __launch_bounds__(256) void k_guess(const float* __restrict__ mat,
                                               int* __restrict__ assign,
                                               int* __restrict__ counts,
                                               int* __restrict__ fail) {
    int i = blockIdx.x * blockDim.x + threadIdx.x;
    if (i >= N_NODE) return;
    int m = i & (N_MOL - 1);
    assign[i] = m;
    atomicAdd(&counts[m], 1);
    if (!(mat[(size_t)m * N_NODE + i] > 0.5f)) atomicAdd(fail, 1);
}

// K0b: full fallback scan (no-op when fail==0). Float4 grid-stride stream.
__global__ __launch_bounds__(256) void k_assign_full(const float4* __restrict__ mat4,
                                                     int* __restrict__ assign,
                                                     const int* __restrict__ fail) {
    if (*fail == 0) return;
    const int total4 = (N_MOL * N_NODE) / 4;
    int stride = gridDim.x * blockDim.x;
    for (int j = blockIdx.x * blockDim.x + threadIdx.x; j < total4; j += stride) {
        float4 v = mat4[j];
        if (v.x > 0.5f || v.y > 0.5f || v.z > 0.5f || v.w > 0.5f) {
            int base = j * 4;
            float f[4] = {v.x, v.y, v.z, v.w};
#pragma unroll
            for (int c = 0; c < 4; ++c) {
                if (f[c] > 0.5f) {
                    int idx = base + c;
                    int m = idx / N_NODE;
                    int i = idx - m * N_NODE;
                    assign[i] = m;
                }
            }
        }
    }
}

// K0c/K0d: guarded fixup when the guess failed (no-ops otherwise)
__global__ __launch_bounds__(256) void k_rezero(int* __restrict__ counts,
                                                const int* __restrict__ fail) {
    if (*fail == 0) return;
    int t = blockIdx.x * blockDim.x + threadIdx.x;
    if (t < N_MOL) counts[t] = 0;
}
__global__ __launch_bounds__(256) void k_recount(const int* __restrict__ assign,
                                                 int* __restrict__ counts,
                                                 const int* __restrict__ fail) {
    if (*fail == 0) return;
    int i = blockIdx.x * blockDim.x + threadIdx.x;
    if (i >= N_NODE) return;
    atomicAdd(&counts[assign[i]], 1);
}

// K1: exclusive prefix sum of counts -> offsets (single block, 1024 threads)
__global__ __launch_bounds__(1024) void k_scan(const int* __restrict__ counts,
                                               int* __restrict__ offsets) {
    __shared__ int s[N_MOL];
    int t = threadIdx.x;
    s[t] = counts[t];
    __syncthreads();
    for (int d = 1; d < N_MOL; d <<= 1) {
        int v = (t >= d) ? s[t - d] : 0;
        __syncthreads();
        s[t] += v;
        __syncthreads();
    }
    offsets[t + 1] = s[t];
    if (t == 0) offsets[0] = 0;
}

// K2: scatter node ids into per-molecule lists (order fixed by K3 sort)
__global__ __launch_bounds__(256) void k_scatter(const int* __restrict__ assign,
                                                 const int* __restrict__ offsets,
                                                 int* __restrict__ cursor,
                                                 int* __restrict__ list) {
    int i = blockIdx.x * blockDim.x + threadIdx.x;
    if (i >= N_NODE) return;
    int m = assign[i];
    int p = atomicAdd(&cursor[m], 1);
    list[offsets[m] + p] = i;
}

// K3: sort each molecule's node list (<=49 elements) by rank for determinism
__global__ __launch_bounds__(64) void k_sort(const int* __restrict__ offsets,
                                             int* __restrict__ list) {
    __shared__ int s[64];
    int m = blockIdx.x;
    int off = offsets[m];
    int cnt = offsets[m + 1] - off;
    int t = threadIdx.x;
    int v = (t < cnt) ? list[off + t] : 0x7fffffff;
    s[t] = v;
    __syncthreads();
    if (t < cnt) {
        int rank = 0;
        for (int j = 0; j < cnt; ++j) rank += (s[j] < v);
        list[off + rank] = v;
    }
}

// K_prep: (a) combined bf16 B matrix [256 x 192] for the fused node GEMM;
//         (b) fp32 transposed GRU weights WihT/WhhT [128 k x 384 row]
//             so the GRU inner loop reads coalesced.
__global__ __launch_bounds__(256) void k_prep(const float* __restrict__ map_W,
                                              const float* __restrict__ att_W,
                                              const float* __restrict__ Wih,
                                              const float* __restrict__ Whh,
                                              short* __restrict__ Bbf,
                                              float* __restrict__ WihT,
                                              float* __restrict__ WhhT) {
    const int NB = 256 * 192;
    const int NT = 128 * 384;
    int idx = blockIdx.x * blockDim.x + threadIdx.x;
    if (idx < NB) {
        int r = idx / 192, k = idx - r * 192;
        float v = 0.f;
        if (r < 128) { if (k < 128) v = map_W[r * 128 + k]; }
        else v = att_W[(size_t)(r - 128) * 192 + k];
        Bbf[idx] = f2bf(v);
    } else if (idx < NB + NT) {
        int j = idx - NB;
        int k = j / 384, r = j - k * 384;
        WihT[j] = Wih[(size_t)r * 128 + k];
    } else if (idx < NB + 2 * NT) {
        int j = idx - NB - NT;
        int k = j / 384, r = j - k * 384;
        WhhT[j] = Whh[(size_t)r * 128 + k];
    }
}

// K4: fused MFMA GEMM: C[50000 x 256] = (node||pos) @ [map_W pad | att_W]^T
// cols 0..127 -> leaky+bias -> mapped ; cols 128..255 -> +bias -> hbuf.
__global__ __launch_bounds__(256) void k_gemm_fused(const float* __restrict__ node,
                                                    const float* __restrict__ pos,
                                                    const short* __restrict__ Bbf,
                                                    const float* __restrict__ map_b,
                                                    const float* __restrict__ att_b,
                                                    float* __restrict__ mapped,
                                                    float* __restrict__ hbuf) {
    __shared__ short sA[64 * 224];
    int t = threadIdx.x;
    int n0 = blockIdx.x * 64;

    for (int idx = t; idx < 64 * 48; idx += 256) {
        int row = idx / 48;
        int c4 = idx - row * 48;
        int gn = n0 + row;
        float4 v = make_float4(0.f, 0.f, 0.f, 0.f);
        if (gn < N_NODE) {
            if (c4 < 32) v = *(const float4*)&node[(size_t)gn * C_DIM + c4 * 4];
            else         v = *(const float4*)&pos[(size_t)gn * P_DIM + (c4 - 32) * 4];
        }
        ushort4 u;
        u.x = (unsigned short)f2bf(v.x);
        u.y = (unsigned short)f2bf(v.y);
        u.z = (unsigned short)f2bf(v.z);
        u.w = (unsigned short)f2bf(v.w);
        *(ushort4*)&sA[row * 224 + c4 * 4] = u;
    }
    __syncthreads();

    int wid = t >> 6, lane = t & 63;
    int wr = wid >> 1, wc = wid & 1;
    int lrow = lane & 15, lk = (lane >> 4) * 8;

    bf16x8 a[2][6];
#pragma unroll
    for (int mt = 0; mt < 2; ++mt)
#pragma unroll
        for (int k = 0; k < 6; ++k)
            a[mt][k] = *(const bf16x8*)&sA[(wr * 32 + mt * 16 + lrow) * 224 + k * 32 + lk];

    f32x4 acc[2][8] = {};
#pragma unroll
    for (int ct = 0; ct < 8; ++ct) {
        int c0 = wc * 128 + ct * 16;
        bf16x8 b[6];
#pragma unroll
        for (int k = 0; k < 6; ++k)
            b[k] = *(const bf16x8*)&Bbf[(size_t)(c0 + lrow) * 192 + k * 32 + lk];
#pragma unroll
        for (int mt = 0; mt < 2; ++mt)
#pragma unroll
            for (int k = 0; k < 6; ++k)
                acc[mt][ct] = __builtin_amdgcn_mfma_f32_16x16x32_bf16(
                    a[mt][k], b[k], acc[mt][ct], 0, 0, 0);
    }

#pragma unroll
    for (int ct = 0; ct < 8; ++ct) {
        int c = wc * 128 + ct * 16 + lrow;
        float bias = (c < 128) ? map_b[c] : att_b[c - 128];
#pragma unroll
        for (int mt = 0; mt < 2; ++mt) {
#pragma unroll
            for (int r = 0; r < 4; ++r) {
                int gn = n0 + wr * 32 + mt * 16 + (lane >> 4) * 4 + r;
                if (gn >= N_NODE) continue;
                float v = acc[mt][ct][r] + bias;
                if (c < 128) {
                    v = (v > 0.f) ? v : 0.01f * v;
                    mapped[(size_t)gn * 128 + c] = v;
                } else {
                    hbuf[(size_t)gn * 128 + (c - 128)] = v;
                }
            }
        }
    }
}

// K5: fused mol0 + BOTH radius iterations (per-molecule independent).
// Block per molecule, 128 threads. Node-id list staged in LDS once.
__global__ __launch_bounds__(128) void k_mol_radius(const float* __restrict__ mapped,
                                                    const float* __restrict__ node,
                                                    const float* __restrict__ pos,
                                                    const float* __restrict__ h,
                                                    const float* __restrict__ alignW,
                                                    const float* __restrict__ alignb,
                                                    const float* __restrict__ WihT,
                                                    const float* __restrict__ WhhT,
                                                    const float* __restrict__ bih,
                                                    const float* __restrict__ bhh,
                                                    const int* __restrict__ offsets,
                                                    const int* __restrict__ list,
                                                    float* __restrict__ mol) {
    __shared__ float s_mol[128];
    __shared__ float s_ctx[128];
    __shared__ float s_red[128];
    __shared__ float s_a[64];
    __shared__ int   s_idx[64];
    int m = blockIdx.x;
    int t = threadIdx.x;
    int off = offsets[m], cnt = offsets[m + 1] - off;   // cnt <= 49

    if (t < cnt) s_idx[t] = list[off + t];
    __syncthreads();

    // phase 0: mol0 = segment-sum of mapped rows
    float molc = 0.f;
    for (int p = 0; p < cnt; ++p)
        molc += mapped[(size_t)s_idx[p] * 128 + t];

    for (int r = 0; r < 2; ++r) {
        s_mol[t] = molc;
        s_red[t] = molc * alignW[t];
        __syncthreads();
        for (int d = 64; d > 0; d >>= 1) {
            if (t < d) s_red[t] += s_red[t + d];
            __syncthreads();
        }
        float dot_mol = s_red[0] + alignb[0];

        int wave = t >> 6, lane = t & 63;
        for (int p = wave; p < cnt; p += 2) {
            int i = s_idx[p];
            float v = pos[(size_t)i * P_DIM + lane] * alignW[128 + lane]
                    + node[(size_t)i * C_DIM + lane] * alignW[192 + lane]
                    + node[(size_t)i * C_DIM + 64 + lane] * alignW[256 + lane];
            for (int d = 32; d > 0; d >>= 1) v += __shfl_down(v, d);
            if (lane == 0) {
                float a = dot_mol + v;
                s_a[p] = (a > 0.f) ? a : 0.01f * a;
            }
        }
        __syncthreads();

        if (t < 64) {
            float x = (t < cnt) ? s_a[t] : -1e30f;
            float mx = x;
            for (int d = 32; d > 0; d >>= 1) mx = fmaxf(mx, __shfl_xor(mx, d));
            float e = (t < cnt) ? __expf(x - mx) : 0.f;
            float sm = e;
            for (int d = 32; d > 0; d >>= 1) sm += __shfl_xor(sm, d);
            if (t < cnt) s_a[t] = e / sm;
        }
        __syncthreads();

        float ctx = 0.f;
        for (int p = 0; p < cnt; ++p)
            ctx += s_a[p] * h[(size_t)s_idx[p] * 128 + t];
        ctx = (ctx > 0.f) ? ctx : (__expf(ctx) - 1.f);
        s_ctx[t] = ctx;
        __syncthreads();

        // GRU: coalesced transposed-weight reads (thread t <-> consecutive addr)
        float gi_r = bih[t],       gh_r = bhh[t];
        float gi_z = bih[128 + t], gh_z = bhh[128 + t];
        float gi_n = bih[256 + t], gh_n = bhh[256 + t];
#pragma unroll 4
        for (int k = 0; k < 128; ++k) {
            float cx = s_ctx[k], hm = s_mol[k];
            const float* wi = &WihT[k * 384];
            const float* wh = &WhhT[k * 384];
            gi_r += cx * wi[t];
            gi_z += cx * wi[128 + t];
            gi_n += cx * wi[256 + t];
            gh_r += hm * wh[t];
            gh_z += hm * wh[128 + t];
            gh_n += hm * wh[256 + t];
        }
        float rr = 1.f / (1.f + __expf(-(gi_r + gh_r)));
        float zz = 1.f / (1.f + __expf(-(gi_z + gh_z)));
        float nn = tanhf(gi_n + rr * gh_n);
        molc = fmaxf((1.f - zz) * nn + zz * molc, 0.f);
        __syncthreads();   // protect s_mol/s_a/s_red before next iteration
    }
    mol[m * 128 + t] = molc;
}

extern "C" void kernel_launch(void* const* d_in, const int* in_sizes, int n_in,
                              void* d_out, int out_size, void* d_ws, size_t ws_size,
                              hipStream_t stream) {
    const float* node   = (const float*)d_in[0];
    const float* pos    = (const float*)d_in[1];
    const float* mat    = (const float*)d_in[2];
    const float* map_W  = (const float*)d_in[4];
    const float* map_b  = (const float*)d_in[5];
    const float* att_W  = (const float*)d_in[6];
    const float* att_b  = (const float*)d_in[7];
    const float* alignW = (const float*)d_in[8];
    const float* alignb = (const float*)d_in[9];
    const float* gWih   = (const float*)d_in[10];
    const float* gWhh   = (const float*)d_in[11];
    const float* gbih   = (const float*)d_in[12];
    const float* gbhh   = (const float*)d_in[13];
    float* mol = (float*)d_out;   // [1024,128]

    size_t o = 0;
    auto alloc = [&](size_t bytes) { size_t r = o; o += (bytes + 255) & ~(size_t)255; return r; };
    char* ws = (char*)d_ws;
    int*   assign  = (int*)(ws + alloc((size_t)N_NODE * 4));
    int*   counts  = (int*)(ws + alloc((size_t)N_MOL * 4));
    int*   cursor  = (int*)(ws + alloc((size_t)N_MOL * 4));
    int*   fail    = (int*)(ws + alloc(4));
    int*   offsets = (int*)(ws + alloc((size_t)(N_MOL + 1) * 4));
    int*   list    = (int*)(ws + alloc((size_t)N_NODE * 4));
    short* Bbf     = (short*)(ws + alloc((size_t)256 * 192 * 2));
    float* WihT    = (float*)(ws + alloc((size_t)128 * 384 * 4));
    float* WhhT    = (float*)(ws + alloc((size_t)128 * 384 * 4));
    float* mapped  = (float*)(ws + alloc((size_t)N_NODE * 128 * 4));
    float* hbuf    = (float*)(ws + alloc((size_t)N_NODE * 128 * 4));

    int nblk = (N_NODE + 255) / 256;
    k_zero<<<4, 256, 0, stream>>>(counts, cursor, fail);
    k_guess<<<nblk, 256, 0, stream>>>(mat, assign, counts, fail);
    k_assign_full<<<2048, 256, 0, stream>>>((const float4*)mat, assign, fail);
    k_rezero<<<4, 256, 0, stream>>>(counts, fail);
    k_recount<<<nblk, 256, 0, stream>>>(assign, counts, fail);
    k_scan<<<1, 1024, 0, stream>>>(counts, offsets);
    k_scatter<<<nblk, 256, 0, stream>>>(assign, offsets, cursor, list);
    k_sort<<<N_MOL, 64, 0, stream>>>(offsets, list);

    int prep_items = 256 * 192 + 2 * 128 * 384;
    k_prep<<<(prep_items + 255) / 256, 256, 0, stream>>>(map_W, att_W, gWih, gWhh,
                                                         Bbf, WihT, WhhT);
    k_gemm_fused<<<(N_NODE + 63) / 64, 256, 0, stream>>>(node, pos, Bbf, map_b, att_b,
                                                         mapped, hbuf);

    k_mol_radius<<<N_MOL, 128, 0, stream>>>(mapped, node, pos, hbuf,
                                            alignW, alignb, WihT, WhhT, gbih, gbhh,
                                            offsets, list, mol);
}